// Round 1
// baseline (341.765 us; speedup 1.0000x reference)
//
#include <hip/hip_runtime.h>

// SynthMorphLoss: soft-dice over int32 label maps + diffusion regularizer.
// B=1, D=160, H=192, W=224, 26 classes (class 0 ignored in dice mean).

namespace {
constexpr int NC  = 26;
constexpr int Dd  = 160, Hh = 192, Ww = 224;
constexpr int NVOX = Dd * Hh * Ww;        // 6,881,280
constexpr int W4   = Ww / 4;              // 56  (224 divisible by 4)
constexpr int HW4  = Hh * W4;             // float4s per (c,d) plane
constexpr int N4F  = 3 * Dd * Hh * W4;    // 5,160,960 float4s in vector field
constexpr int N4L  = NVOX / 4;            // 1,720,320 int4s per label map
}

__global__ void init_ws_kernel(unsigned int* __restrict__ counts,
                               double* __restrict__ sums) {
    int i = threadIdx.x;
    if (i < 3 * NC) counts[i] = 0u;
    if (i < 3)      sums[i]   = 0.0;
}

// Per-block LDS-privatized histogram of fixed / moving / intersection counts.
__global__ void hist_kernel(const int4* __restrict__ f4,
                            const int4* __restrict__ m4,
                            unsigned int* __restrict__ gc) {
    __shared__ unsigned int h[3 * NC];
    for (int i = threadIdx.x; i < 3 * NC; i += blockDim.x) h[i] = 0u;
    __syncthreads();

    const int stride = gridDim.x * blockDim.x;
    for (int i = blockIdx.x * blockDim.x + threadIdx.x; i < N4L; i += stride) {
        int4 a = f4[i];
        int4 b = m4[i];
        atomicAdd(&h[a.x], 1u); atomicAdd(&h[NC + b.x], 1u); if (a.x == b.x) atomicAdd(&h[2 * NC + a.x], 1u);
        atomicAdd(&h[a.y], 1u); atomicAdd(&h[NC + b.y], 1u); if (a.y == b.y) atomicAdd(&h[2 * NC + a.y], 1u);
        atomicAdd(&h[a.z], 1u); atomicAdd(&h[NC + b.z], 1u); if (a.z == b.z) atomicAdd(&h[2 * NC + a.z], 1u);
        atomicAdd(&h[a.w], 1u); atomicAdd(&h[NC + b.w], 1u); if (a.w == b.w) atomicAdd(&h[2 * NC + a.w], 1u);
    }
    __syncthreads();
    for (int i = threadIdx.x; i < 3 * NC; i += blockDim.x)
        if (h[i]) atomicAdd(&gc[i], h[i]);
}

// Diffusion: sum of squared forward differences along x (W), y (H), z (D).
// One thread per float4 along W; neighbor loads for +W (dy) and +H*W (dz)
// hit L1/L2 (reuse distance 896 B / 172 KB).
__global__ void diff_kernel(const float* __restrict__ vf,
                            double* __restrict__ gs) {
    const float4* __restrict__ v4p = (const float4*)vf;
    float sx = 0.f, sy = 0.f, sz = 0.f;
    const int stride = gridDim.x * blockDim.x;
    for (int i = blockIdx.x * blockDim.x + threadIdx.x; i < N4F; i += stride) {
        float4 v = v4p[i];
        int w4   = i % W4;
        int rest = i / W4;      // cd*H + h
        int h    = rest % Hh;
        int cd   = rest / Hh;   // c*D + d
        int d    = cd % Dd;

        // dx: 3 interior diffs + 1 crossing diff into the next float4
        float d1 = v.y - v.x, d2 = v.z - v.y, d3 = v.w - v.z;
        sx += d1 * d1 + d2 * d2 + d3 * d3;
        if (w4 != W4 - 1) {
            float nx = vf[4 * i + 4];
            float d4 = nx - v.w;
            sx += d4 * d4;
        }
        // dy
        if (h != Hh - 1) {
            float4 u = v4p[i + W4];
            float e0 = u.x - v.x, e1 = u.y - v.y, e2 = u.z - v.z, e3 = u.w - v.w;
            sy += e0 * e0 + e1 * e1 + e2 * e2 + e3 * e3;
        }
        // dz (valid only when d+1 stays within the same channel)
        if (d != Dd - 1) {
            float4 u = v4p[i + HW4];
            float e0 = u.x - v.x, e1 = u.y - v.y, e2 = u.z - v.z, e3 = u.w - v.w;
            sz += e0 * e0 + e1 * e1 + e2 * e2 + e3 * e3;
        }
    }

    // wave64 shuffle reduction
    #pragma unroll
    for (int off = 32; off > 0; off >>= 1) {
        sx += __shfl_down(sx, off);
        sy += __shfl_down(sy, off);
        sz += __shfl_down(sz, off);
    }
    __shared__ float px[4], py[4], pz[4];   // blockDim = 256 -> 4 waves
    int lane = threadIdx.x & 63;
    int wid  = threadIdx.x >> 6;
    if (lane == 0) { px[wid] = sx; py[wid] = sy; pz[wid] = sz; }
    __syncthreads();
    if (threadIdx.x == 0) {
        float tx = px[0] + px[1] + px[2] + px[3];
        float ty = py[0] + py[1] + py[2] + py[3];
        float tz = pz[0] + pz[1] + pz[2] + pz[3];
        atomicAdd(&gs[0], (double)tx);
        atomicAdd(&gs[1], (double)ty);
        atomicAdd(&gs[2], (double)tz);
    }
}

__global__ void finalize_kernel(const unsigned int* __restrict__ gc,
                                const double* __restrict__ gs,
                                float* __restrict__ out) {
    if (threadIdx.x == 0 && blockIdx.x == 0) {
        float dsum = 0.f;
        for (int c = 1; c < NC; ++c) {   // skip ignore class 0
            float fv = (float)gc[c];
            float mv = (float)gc[NC + c];
            float iv = (float)gc[2 * NC + c];
            dsum += (2.f * iv + 1e-5f) / (fv + mv + 1e-5f);
        }
        float sim = 1.f - dsum * (1.f / 25.f);
        double mdx = gs[0] / ((double)3 * Dd * Hh * (Ww - 1));
        double mdy = gs[1] / ((double)3 * Dd * (Hh - 1) * Ww);
        double mdz = gs[2] / ((double)3 * (Dd - 1) * Hh * Ww);
        float smooth = (float)((mdx + mdy + mdz) / 3.0);
        out[0] = sim + smooth;
        out[1] = sim;
        out[2] = smooth;
    }
}

extern "C" void kernel_launch(void* const* d_in, const int* in_sizes, int n_in,
                              void* d_out, int out_size, void* d_ws, size_t ws_size,
                              hipStream_t stream) {
    const int*   fl = (const int*)d_in[0];
    const int*   ml = (const int*)d_in[1];
    const float* vf = (const float*)d_in[2];
    float* out = (float*)d_out;

    // workspace: [0,312) uint counts (3*26), [512,536) double sums[3]
    unsigned int* counts = (unsigned int*)d_ws;
    double*       sums   = (double*)((char*)d_ws + 512);

    init_ws_kernel<<<1, 128, 0, stream>>>(counts, sums);
    hist_kernel<<<2048, 256, 0, stream>>>((const int4*)fl, (const int4*)ml, counts);
    diff_kernel<<<4096, 256, 0, stream>>>(vf, sums);
    finalize_kernel<<<1, 64, 0, stream>>>(counts, sums, out);
}

// Round 2
// 255.364 us; speedup vs baseline: 1.3383x; 1.3383x over previous
//
#include <hip/hip_runtime.h>

// SynthMorphLoss: soft-dice over int32 label maps + diffusion regularizer.
// B=1, D=160, H=192, W=224, 26 classes (class 0 ignored in dice mean).

namespace {
constexpr int NC   = 26;
constexpr int Dd   = 160, Hh = 192, Ww = 224;
constexpr int W4   = Ww / 4;            // 56 float4 per row
constexpr int NROWS = 3 * Dd * Hh;      // 92,160 rows in the vector field
constexpr int N4L  = Dd * Hh * Ww / 4;  // 1,720,320 int4 per label map
// joint histogram: key = f*33 + m  (stride 33 so bank = (f+m)%32, mixes both)
constexpr int JSTRIDE = 33;
constexpr int NBINS   = NC * JSTRIDE;   // 858
}

__global__ void init_ws_kernel(unsigned int* __restrict__ joint,
                               double* __restrict__ sums) {
    int i = blockIdx.x * blockDim.x + threadIdx.x;
    if (i < NBINS) joint[i] = 0u;
    if (i < 3)     sums[i]  = 0.0;
}

// Joint histogram of (fixed,moving) label pairs: one LDS atomic per voxel,
// ~676 live bins so same-address serialization within a wave is ~1.1-way.
__global__ void hist_kernel(const int4* __restrict__ f4,
                            const int4* __restrict__ m4,
                            unsigned int* __restrict__ gj) {
    __shared__ unsigned int h[NBINS];
    for (int i = threadIdx.x; i < NBINS; i += blockDim.x) h[i] = 0u;
    __syncthreads();

    const int stride = gridDim.x * blockDim.x;
    for (int i = blockIdx.x * blockDim.x + threadIdx.x; i < N4L; i += stride) {
        int4 a = f4[i];
        int4 b = m4[i];
        atomicAdd(&h[a.x * JSTRIDE + b.x], 1u);
        atomicAdd(&h[a.y * JSTRIDE + b.y], 1u);
        atomicAdd(&h[a.z * JSTRIDE + b.z], 1u);
        atomicAdd(&h[a.w * JSTRIDE + b.w], 1u);
    }
    __syncthreads();
    for (int i = threadIdx.x; i < NBINS; i += blockDim.x) {
        unsigned int v = h[i];
        if (v) atomicAdd(&gj[i], v);
    }
}

// Diffusion: wave-per-row-chunk. Row = 56 float4 (lanes 0..55 active).
// dx via __shfl_down within the row; dy via next row's load (which rotates
// into `cur` next iteration -> 2 global loads per row); dz via +Hh rows.
// h/d tracked incrementally: no div/mod, dy/dz branches wave-uniform.
__global__ void diff_kernel(const float4* __restrict__ v4,
                            double* __restrict__ gs) {
    const int lane   = threadIdx.x & 63;
    const int gwave  = (blockIdx.x * blockDim.x + threadIdx.x) >> 6;
    const int nwaves = (gridDim.x * blockDim.x) >> 6;
    const int chunk  = (NROWS + nwaves - 1) / nwaves;

    float sx = 0.f, sy = 0.f, sz = 0.f;
    int r0 = gwave * chunk;
    int r1 = min(r0 + chunk, NROWS);
    if (r0 < r1) {
        int h  = r0 % Hh;
        int cd = r0 / Hh;
        int d  = cd % Dd;
        const bool al = (lane < W4);
        const float4 zero4 = make_float4(0.f, 0.f, 0.f, 0.f);
        float4 cur = al ? v4[(size_t)r0 * W4 + lane] : zero4;

        for (int r = r0; r < r1; ++r) {
            int rn = (r + 1 < NROWS) ? (r + 1) : r;           // clamp last row
            float4 nxt = al ? v4[(size_t)rn * W4 + lane] : zero4;

            // dx: 3 interior diffs + crossing diff from lane+1's x
            float d1 = cur.y - cur.x, d2 = cur.z - cur.y, d3 = cur.w - cur.z;
            float nx = __shfl_down(cur.x, 1);
            sx += d1 * d1 + d2 * d2 + d3 * d3;
            if (lane < W4 - 1) {                               // lanes 0..54
                float d4 = nx - cur.w;
                sx += d4 * d4;
            }
            // dy (wave-uniform branch)
            if (h < Hh - 1) {
                float e0 = nxt.x - cur.x, e1 = nxt.y - cur.y;
                float e2 = nxt.z - cur.z, e3 = nxt.w - cur.w;
                sy += e0 * e0 + e1 * e1 + e2 * e2 + e3 * e3;
            }
            // dz (wave-uniform branch; +1 in d = +Hh rows)
            if (d < Dd - 1) {
                float4 zr = al ? v4[(size_t)(r + Hh) * W4 + lane] : zero4;
                float e0 = zr.x - cur.x, e1 = zr.y - cur.y;
                float e2 = zr.z - cur.z, e3 = zr.w - cur.w;
                sz += e0 * e0 + e1 * e1 + e2 * e2 + e3 * e3;
            }
            cur = nxt;
            if (++h == Hh) { h = 0; if (++d == Dd) d = 0; }
        }
    }

    // wave64 shuffle reduction, then LDS across the block's 4 waves
    #pragma unroll
    for (int off = 32; off > 0; off >>= 1) {
        sx += __shfl_down(sx, off);
        sy += __shfl_down(sy, off);
        sz += __shfl_down(sz, off);
    }
    __shared__ float px[4], py[4], pz[4];
    int wid = threadIdx.x >> 6;
    if (lane == 0) { px[wid] = sx; py[wid] = sy; pz[wid] = sz; }
    __syncthreads();
    if (threadIdx.x == 0) {
        atomicAdd(&gs[0], (double)(px[0] + px[1] + px[2] + px[3]));
        atomicAdd(&gs[1], (double)(py[0] + py[1] + py[2] + py[3]));
        atomicAdd(&gs[2], (double)(pz[0] + pz[1] + pz[2] + pz[3]));
    }
}

__global__ void finalize_kernel(const unsigned int* __restrict__ gj,
                                const double* __restrict__ gs,
                                float* __restrict__ out) {
    // one wave: lane c (1..25) computes its class's dice term
    int lane = threadIdx.x & 63;
    float term = 0.f;
    if (lane >= 1 && lane < NC) {
        float fv = 0.f, mv = 0.f;
        #pragma unroll
        for (int m = 0; m < NC; ++m) fv += (float)gj[lane * JSTRIDE + m];
        #pragma unroll
        for (int f = 0; f < NC; ++f) mv += (float)gj[f * JSTRIDE + lane];
        float iv = (float)gj[lane * JSTRIDE + lane];
        term = (2.f * iv + 1e-5f) / (fv + mv + 1e-5f);
    }
    #pragma unroll
    for (int off = 32; off > 0; off >>= 1) term += __shfl_down(term, off);
    if (threadIdx.x == 0 && blockIdx.x == 0) {
        float sim = 1.f - term * (1.f / 25.f);
        double mdx = gs[0] / ((double)3 * Dd * Hh * (Ww - 1));
        double mdy = gs[1] / ((double)3 * Dd * (Hh - 1) * Ww);
        double mdz = gs[2] / ((double)3 * (Dd - 1) * Hh * Ww);
        float smooth = (float)((mdx + mdy + mdz) / 3.0);
        out[0] = sim + smooth;
        out[1] = sim;
        out[2] = smooth;
    }
}

extern "C" void kernel_launch(void* const* d_in, const int* in_sizes, int n_in,
                              void* d_out, int out_size, void* d_ws, size_t ws_size,
                              hipStream_t stream) {
    const int*   fl = (const int*)d_in[0];
    const int*   ml = (const int*)d_in[1];
    const float* vf = (const float*)d_in[2];
    float* out = (float*)d_out;

    // workspace: [0, 3432) joint counts (858 uints); [3584, 3608) double sums[3]
    unsigned int* joint = (unsigned int*)d_ws;
    double*       sums  = (double*)((char*)d_ws + 3584);

    init_ws_kernel<<<1, 1024, 0, stream>>>(joint, sums);
    hist_kernel<<<1024, 256, 0, stream>>>((const int4*)fl, (const int4*)ml, joint);
    diff_kernel<<<2048, 256, 0, stream>>>((const float4*)vf, sums);
    finalize_kernel<<<1, 64, 0, stream>>>(joint, sums, out);
}

// Round 3
// 251.308 us; speedup vs baseline: 1.3599x; 1.0161x over previous
//
#include <hip/hip_runtime.h>

// SynthMorphLoss: soft-dice over int32 label maps + diffusion regularizer.
// B=1, D=160, H=192, W=224, 26 classes (class 0 ignored in dice mean).
// R3: MLP-batched loads (8 independent loads in flight per wave before any
// consume) in both hot kernels — R2 counters showed ~1 TB/s plateau with
// VALUBusy 7.5% and no over-fetch => request-concurrency bound.

namespace {
constexpr int NC   = 26;
constexpr int Dd   = 160, Hh = 192, Ww = 224;
constexpr int W4   = Ww / 4;              // 56 float4 per row
constexpr int NROWS = 3 * Dd * Hh;        // 92,160 rows in the vector field
constexpr int N4L  = Dd * Hh * Ww / 4;    // 1,720,320 int4 per label map
// joint histogram: key = f*33 + m (stride 33 mixes both labels into banks)
constexpr int JSTRIDE = 33;
constexpr int NBINS   = NC * JSTRIDE;     // 858
constexpr int HIST_BLOCKS  = 1680;        // 1680*256*4 == N4L exactly
constexpr int HIST_THREADS = HIST_BLOCKS * 256;   // 430,080
constexpr int ROWS_PER_WAVE = 12;         // divides Hh -> no plane crossing
constexpr int DIFF_BLOCKS  = 1920;        // 7680 waves * 12 rows == NROWS
}

__global__ void init_ws_kernel(unsigned int* __restrict__ joint,
                               double* __restrict__ sums) {
    int i = blockIdx.x * blockDim.x + threadIdx.x;
    if (i < NBINS) joint[i] = 0u;
    if (i < 3)     sums[i]  = 0.0;
}

// Joint histogram: each thread loads 4 int4 from each map (8 independent
// global loads in flight), then 16 LDS atomics (no wait needed).
__global__ __launch_bounds__(256) void hist_kernel(const int4* __restrict__ f4,
                                                   const int4* __restrict__ m4,
                                                   unsigned int* __restrict__ gj) {
    __shared__ unsigned int h[NBINS];
    for (int i = threadIdx.x; i < NBINS; i += 256) h[i] = 0u;
    __syncthreads();

    const int g = blockIdx.x * 256 + threadIdx.x;
    int4 a0 = f4[g];
    int4 a1 = f4[g + HIST_THREADS];
    int4 a2 = f4[g + 2 * HIST_THREADS];
    int4 a3 = f4[g + 3 * HIST_THREADS];
    int4 b0 = m4[g];
    int4 b1 = m4[g + HIST_THREADS];
    int4 b2 = m4[g + 2 * HIST_THREADS];
    int4 b3 = m4[g + 3 * HIST_THREADS];

#define JACC(A, B)                                   \
    atomicAdd(&h[(A).x * JSTRIDE + (B).x], 1u);      \
    atomicAdd(&h[(A).y * JSTRIDE + (B).y], 1u);      \
    atomicAdd(&h[(A).z * JSTRIDE + (B).z], 1u);      \
    atomicAdd(&h[(A).w * JSTRIDE + (B).w], 1u);
    JACC(a0, b0) JACC(a1, b1) JACC(a2, b2) JACC(a3, b3)
#undef JACC

    __syncthreads();
    for (int i = threadIdx.x; i < NBINS; i += 256) {
        unsigned int v = h[i];
        if (v) atomicAdd(&gj[i], v);
    }
}

// Diffusion: wave-per-12-rows (one h-slab, never crosses plane boundary),
// unrolled 4 rows per group: 4 next-row + 4 z-neighbor loads issued together.
__global__ __launch_bounds__(256) void diff_kernel(const float4* __restrict__ v4,
                                                   double* __restrict__ gs) {
    const int lane  = threadIdx.x & 63;
    const int gwave = (blockIdx.x * 256 + threadIdx.x) >> 6;
    const int r0    = gwave * ROWS_PER_WAVE;
    const int h0    = r0 % Hh;                 // multiple of 12
    const int d     = (r0 / Hh) % Dd;          // constant for the wave
    const bool al   = (lane < W4);
    const bool dzv  = (d < Dd - 1);            // wave-constant dz validity
    const float4 z4 = make_float4(0.f, 0.f, 0.f, 0.f);

    float sx = 0.f, sy = 0.f, sz = 0.f;

    float4 cur = al ? v4[(size_t)r0 * W4 + lane] : z4;

    for (int grp = 0; grp < ROWS_PER_WAVE / 4; ++grp) {
        const int R = r0 + 4 * grp;
        // --- issue 8 independent loads ---
        float4 n1 = al ? v4[(size_t)(R + 1) * W4 + lane] : z4;
        float4 n2 = al ? v4[(size_t)(R + 2) * W4 + lane] : z4;
        float4 n3 = al ? v4[(size_t)(R + 3) * W4 + lane] : z4;
        const int r4 = (R + 4 < NROWS) ? (R + 4) : (NROWS - 1);
        float4 n4 = al ? v4[(size_t)r4 * W4 + lane] : z4;
        float4 q0 = z4, q1 = z4, q2 = z4, q3 = z4;
        if (dzv) {
            q0 = al ? v4[(size_t)(R + 0 + Hh) * W4 + lane] : z4;
            q1 = al ? v4[(size_t)(R + 1 + Hh) * W4 + lane] : z4;
            q2 = al ? v4[(size_t)(R + 2 + Hh) * W4 + lane] : z4;
            q3 = al ? v4[(size_t)(R + 3 + Hh) * W4 + lane] : z4;
        }
        // --- compute 4 rows ---
        const int hbase = h0 + 4 * grp;
#define ROW(A, B, Q, J)                                                        \
        {                                                                      \
            float d1 = (A).y - (A).x, d2 = (A).z - (A).y, d3 = (A).w - (A).z;  \
            sx += d1 * d1 + d2 * d2 + d3 * d3;                                 \
            float nx = __shfl_down((A).x, 1);                                  \
            if (lane < W4 - 1) { float d4 = nx - (A).w; sx += d4 * d4; }       \
            if (hbase + (J) != Hh - 1) {                                       \
                float e0 = (B).x - (A).x, e1 = (B).y - (A).y;                  \
                float e2 = (B).z - (A).z, e3 = (B).w - (A).w;                  \
                sy += e0 * e0 + e1 * e1 + e2 * e2 + e3 * e3;                   \
            }                                                                  \
            if (dzv) {                                                         \
                float e0 = (Q).x - (A).x, e1 = (Q).y - (A).y;                  \
                float e2 = (Q).z - (A).z, e3 = (Q).w - (A).w;                  \
                sz += e0 * e0 + e1 * e1 + e2 * e2 + e3 * e3;                   \
            }                                                                  \
        }
        ROW(cur, n1, q0, 0)
        ROW(n1,  n2, q1, 1)
        ROW(n2,  n3, q2, 2)
        ROW(n3,  n4, q3, 3)
#undef ROW
        cur = n4;
    }

    // wave64 shuffle reduction, then LDS across the block's 4 waves
    #pragma unroll
    for (int off = 32; off > 0; off >>= 1) {
        sx += __shfl_down(sx, off);
        sy += __shfl_down(sy, off);
        sz += __shfl_down(sz, off);
    }
    __shared__ float px[4], py[4], pz[4];
    int wid = threadIdx.x >> 6;
    if (lane == 0) { px[wid] = sx; py[wid] = sy; pz[wid] = sz; }
    __syncthreads();
    if (threadIdx.x == 0) {
        atomicAdd(&gs[0], (double)(px[0] + px[1] + px[2] + px[3]));
        atomicAdd(&gs[1], (double)(py[0] + py[1] + py[2] + py[3]));
        atomicAdd(&gs[2], (double)(pz[0] + pz[1] + pz[2] + pz[3]));
    }
}

__global__ void finalize_kernel(const unsigned int* __restrict__ gj,
                                const double* __restrict__ gs,
                                float* __restrict__ out) {
    int lane = threadIdx.x & 63;
    float term = 0.f;
    if (lane >= 1 && lane < NC) {
        float fv = 0.f, mv = 0.f;
        #pragma unroll
        for (int m = 0; m < NC; ++m) fv += (float)gj[lane * JSTRIDE + m];
        #pragma unroll
        for (int f = 0; f < NC; ++f) mv += (float)gj[f * JSTRIDE + lane];
        float iv = (float)gj[lane * JSTRIDE + lane];
        term = (2.f * iv + 1e-5f) / (fv + mv + 1e-5f);
    }
    #pragma unroll
    for (int off = 32; off > 0; off >>= 1) term += __shfl_down(term, off);
    if (threadIdx.x == 0 && blockIdx.x == 0) {
        float sim = 1.f - term * (1.f / 25.f);
        double mdx = gs[0] / ((double)3 * Dd * Hh * (Ww - 1));
        double mdy = gs[1] / ((double)3 * Dd * (Hh - 1) * Ww);
        double mdz = gs[2] / ((double)3 * (Dd - 1) * Hh * Ww);
        float smooth = (float)((mdx + mdy + mdz) / 3.0);
        out[0] = sim + smooth;
        out[1] = sim;
        out[2] = smooth;
    }
}

extern "C" void kernel_launch(void* const* d_in, const int* in_sizes, int n_in,
                              void* d_out, int out_size, void* d_ws, size_t ws_size,
                              hipStream_t stream) {
    const int*   fl = (const int*)d_in[0];
    const int*   ml = (const int*)d_in[1];
    const float* vf = (const float*)d_in[2];
    float* out = (float*)d_out;

    // workspace: [0, 3432) joint counts (858 uints); [3584, 3608) double sums[3]
    unsigned int* joint = (unsigned int*)d_ws;
    double*       sums  = (double*)((char*)d_ws + 3584);

    init_ws_kernel<<<1, 1024, 0, stream>>>(joint, sums);
    hist_kernel<<<HIST_BLOCKS, 256, 0, stream>>>((const int4*)fl, (const int4*)ml, joint);
    diff_kernel<<<DIFF_BLOCKS, 256, 0, stream>>>((const float4*)vf, sums);
    finalize_kernel<<<1, 64, 0, stream>>>(joint, sums, out);
}